// Round 3
// baseline (1045.265 us; speedup 1.0000x reference)
//
#include <hip/hip_runtime.h>
#include <hip/hip_bf16.h>

typedef __hip_bfloat16 bf16;
typedef __attribute__((ext_vector_type(8))) short bshort8;
typedef __attribute__((ext_vector_type(4))) float float4v;

#define N_NODES 10000
#define N_EDGES 320000
#define IN_DIM  128
#define HID_DIM 256
#define OUT_DIM 128

// ---- d_out layout (fp32 elements) ----
// out_x : floats [0          , 1,280,000)    bytes [0          , 5,120,000)
// out_s : floats [1,280,000  , 101,280,000)  bytes [5,120,000  , 405,120,000)
// out_h : floats [101,280,000, 102,560,000)  bytes [405,120,000, 410,240,000)
//
// Scratch lives inside the out_s byte-region (dead before k_sgemm writes it);
// hs (bf16 staging of h_) lives in the out_h region (overwritten by the final
// h-passthrough memcpy AFTER k_sgemm has consumed it). d_ws is deliberately
// unused (ws_size not guaranteed sufficient).
#define SC_BUF1 5120000ull     // 10000x256 f32 = 10,240,000 B
#define SC_BUF2 15360000ull    // 10000x256 f32 = 10,240,000 B
#define SC_ESRC 25600000ull    // 320000 i32    =  1,280,000 B
#define SC_CNT  26880000ull    // 10000 i32
#define SC_CUR  26920192ull    // 10000 i32
#define SC_RPTR 26960384ull    // 10001 i32
#define SC_DINV 27000576ull    // 10000 f32  (ends 27,040,576 << 405,120,000)
#define OFF_HS  405120000ull   // 10000x128 bf16 = 2,560,000 B (inside out_h's 5.12 MB)

__global__ void k_zero(int* __restrict__ cnt, int* __restrict__ cur) {
    int i = blockIdx.x * blockDim.x + threadIdx.x;
    if (i < N_NODES) { cnt[i] = 0; cur[i] = 0; }
}

__global__ void k_hist(const int* __restrict__ dst, int* __restrict__ cnt) {
    int e = blockIdx.x * blockDim.x + threadIdx.x;
    if (e < N_EDGES) {
        int d = dst[e];
        if ((unsigned)d < N_NODES) atomicAdd(&cnt[d], 1);
    }
}

// single-block exclusive scan over 10000 counts + dinv = rsqrt(deg), deg=cnt+1 (self-loop)
__global__ void k_scan(const int* __restrict__ cnt, int* __restrict__ rptr,
                       float* __restrict__ dinv) {
    __shared__ int sums[1024];
    int t = threadIdx.x;
    int base_n = t * 10;
    int loc[10];
    int s = 0;
    for (int i = 0; i < 10; i++) {
        int n = base_n + i;
        int c = (n < N_NODES) ? cnt[n] : 0;
        loc[i] = s;
        s += c;
        if (n < N_NODES) dinv[n] = rsqrtf((float)(c + 1));
    }
    sums[t] = s;
    __syncthreads();
    for (int off = 1; off < 1024; off <<= 1) {
        int v = (t >= off) ? sums[t - off] : 0;
        __syncthreads();
        sums[t] += v;
        __syncthreads();
    }
    int basev = (t == 0) ? 0 : sums[t - 1];
    for (int i = 0; i < 10; i++) {
        int n = base_n + i;
        if (n < N_NODES) rptr[n] = basev + loc[i];
    }
    if (t == 0) rptr[N_NODES] = N_EDGES;
}

__global__ void k_fill(const int* __restrict__ src, const int* __restrict__ dst,
                       const int* __restrict__ rptr, int* __restrict__ cur,
                       int* __restrict__ esrc) {
    int e = blockIdx.x * blockDim.x + threadIdx.x;
    if (e < N_EDGES) {
        int d = dst[e];
        if ((unsigned)d >= N_NODES) return;
        int p = rptr[d] + atomicAdd(&cur[d], 1);
        if ((unsigned)p < N_EDGES) esrc[p] = src[e];
    }
}

// out[n,f] = sum_k x[n,k] * W[k,f]   (all fp32)
template <int K, int F>
__global__ void k_linear(const float* __restrict__ x, const float* __restrict__ W,
                         float* __restrict__ out) {
    int idx = blockIdx.x * blockDim.x + threadIdx.x;
    if (idx >= N_NODES * F) return;
    int n = idx / F, f = idx % F;
    const float* xr = x + n * K;
    float acc = 0.f;
#pragma unroll 8
    for (int k = 0; k < K; k++) acc += xr[k] * W[k * F + f];
    out[idx] = acc;
}

// CSR aggregate: out[n] = dinv[n]^2*xw[n] + sum_e dinv[src]*dinv[n]*xw[src] + b
template <int F, bool RELU>
__global__ void k_aggregate(const float* __restrict__ xw, const float* __restrict__ dinv,
                            const int* __restrict__ rptr, const int* __restrict__ esrc,
                            const float* __restrict__ bias,
                            float* __restrict__ outf, bf16* __restrict__ outb) {
    int n = blockIdx.x;
    int f = threadIdx.x;
    float dn = dinv[n];
    float acc = dn * dn * xw[n * F + f];
    int e0 = rptr[n], e1 = rptr[n + 1];
    for (int e = e0; e < e1; e++) {
        int s = esrc[e];
        if ((unsigned)s >= N_NODES) s = 0;  // defensive
        acc += dn * dinv[s] * xw[s * F + f];
    }
    acc += bias[f];
    if (RELU) acc = fmaxf(acc, 0.f);
    if (outf) outf[n * F + f] = acc;
    if (outb) outb[n * F + f] = __float2bfloat16(acc);
}

// S = H * H^T, H: [N_NODES,128] bf16 staging, S: [N_NODES,N_NODES] fp32.
// wave computes a 64x64 block (4x4 tiles of 16x16x32 MFMA); block = 4 waves -> 128x128.
// A-frag and B-frag share the lane layout row=lane&15, k=(lane>>4)*8+j (B = H too).
// (S symmetric -> robust to any C/D row/col-swap concern.)
__global__ __launch_bounds__(256) void k_sgemm(const bf16* __restrict__ H,
                                               float* __restrict__ S) {
    int w = threadIdx.x >> 6;
    int lane = threadIdx.x & 63;
    int i0 = blockIdx.y * 128 + (w & 1) * 64;
    int j0 = blockIdx.x * 128 + (w >> 1) * 64;
    int l15 = lane & 15;
    int quad = lane >> 4;

    float4v acc[4][4];
    for (int a = 0; a < 4; a++)
        for (int b = 0; b < 4; b++)
            acc[a][b] = (float4v){0.f, 0.f, 0.f, 0.f};

    const short* Hs = (const short*)H;
    for (int kk = 0; kk < 4; kk++) {
        int ko = kk * 32 + quad * 8;
        bshort8 af[4], bfr[4];
#pragma unroll
        for (int t = 0; t < 4; t++) {
            int r = i0 + t * 16 + l15;
            if (r >= N_NODES) r = 0;
            af[t] = *(const bshort8*)(Hs + r * IN_DIM + ko);
            int c = j0 + t * 16 + l15;
            if (c >= N_NODES) c = 0;
            bfr[t] = *(const bshort8*)(Hs + c * IN_DIM + ko);
        }
#pragma unroll
        for (int ti = 0; ti < 4; ti++)
#pragma unroll
            for (int tj = 0; tj < 4; tj++)
                acc[ti][tj] = __builtin_amdgcn_mfma_f32_16x16x32_bf16(
                    af[ti], bfr[tj], acc[ti][tj], 0, 0, 0);
    }

#pragma unroll
    for (int ti = 0; ti < 4; ti++) {
#pragma unroll
        for (int tj = 0; tj < 4; tj++) {
            int col = j0 + tj * 16 + l15;
            if (col >= N_NODES) continue;
#pragma unroll
            for (int r = 0; r < 4; r++) {
                int row = i0 + ti * 16 + quad * 4 + r;
                if (row < N_NODES)
                    S[(size_t)row * N_NODES + col] = acc[ti][tj][r];
            }
        }
    }
}

extern "C" void kernel_launch(void* const* d_in, const int* in_sizes, int n_in,
                              void* d_out, int out_size, void* d_ws, size_t ws_size,
                              hipStream_t stream) {
    const float* h   = (const float*)d_in[0];
    const float* W1a = (const float*)d_in[1];
    const float* b1a = (const float*)d_in[2];
    const float* W2a = (const float*)d_in[3];
    const float* b2a = (const float*)d_in[4];
    const float* W1s = (const float*)d_in[5];
    const float* b1s = (const float*)d_in[6];
    const float* W2s = (const float*)d_in[7];
    const float* b2s = (const float*)d_in[8];
    const int* edge  = (const int*)d_in[9];
    const int* src = edge;
    const int* dst = edge + N_EDGES;

    char* ob = (char*)d_out;
    float* buf1 = (float*)(ob + SC_BUF1);
    float* buf2 = (float*)(ob + SC_BUF2);
    int*   esrc = (int*)(ob + SC_ESRC);
    int*   cnt  = (int*)(ob + SC_CNT);
    int*   cur  = (int*)(ob + SC_CUR);
    int*   rptr = (int*)(ob + SC_RPTR);
    float* dinv = (float*)(ob + SC_DINV);
    bf16*  hs   = (bf16*)(ob + OFF_HS);   // staged in out_h region

    float* out   = (float*)d_out;
    float* out_x = out;                                   // [10000,128]
    float* out_s = out + (size_t)N_NODES * OUT_DIM;       // [10000,10000]
    float* out_h = out_s + (size_t)N_NODES * N_NODES;     // [10000,128]

    // graph prep: degree histogram -> scan -> CSR fill
    k_zero<<<(N_NODES + 255) / 256, 256, 0, stream>>>(cnt, cur);
    k_hist<<<(N_EDGES + 255) / 256, 256, 0, stream>>>(dst, cnt);
    k_scan<<<1, 1024, 0, stream>>>(cnt, rptr, dinv);
    k_fill<<<(N_EDGES + 255) / 256, 256, 0, stream>>>(src, dst, rptr, cur, esrc);

    // two GCN branches: attribute (-> out_x fp32), structure (-> hs bf16)
    for (int br = 0; br < 2; br++) {
        const float* W1 = br ? W1s : W1a;
        const float* b1 = br ? b1s : b1a;
        const float* W2 = br ? W2s : W2a;
        const float* b2 = br ? b2s : b2a;

        // layer 1: linear + aggregate + relu -> buf2 [10000,256] f32
        k_linear<IN_DIM, HID_DIM>
            <<<(N_NODES * HID_DIM) / 256, 256, 0, stream>>>(h, W1, buf1);
        k_aggregate<HID_DIM, true>
            <<<N_NODES, HID_DIM, 0, stream>>>(buf1, dinv, rptr, esrc, b1, buf2, nullptr);
        // layer 2: linear + aggregate (no relu) -> final
        k_linear<HID_DIM, OUT_DIM>
            <<<(N_NODES * OUT_DIM) / 256, 256, 0, stream>>>(buf2, W2, buf1);
        if (br == 0)
            k_aggregate<OUT_DIM, false>
                <<<N_NODES, OUT_DIM, 0, stream>>>(buf1, dinv, rptr, esrc, b2, out_x, nullptr);
        else
            k_aggregate<OUT_DIM, false>
                <<<N_NODES, OUT_DIM, 0, stream>>>(buf1, dinv, rptr, esrc, b2, nullptr, hs);
    }

    // s_ = h_ @ h_^T  (reads bf16 hs from out_h region, writes fp32 out_s)
    dim3 g((N_NODES + 127) / 128, (N_NODES + 127) / 128);
    k_sgemm<<<g, 256, 0, stream>>>(hs, out_s);

    // third output: h passthrough (overwrites hs staging in out_h)
    hipMemcpyAsync(out_h, h, (size_t)N_NODES * IN_DIM * sizeof(float),
                   hipMemcpyDeviceToDevice, stream);
}